// Round 1
// 130.891 us; speedup vs baseline: 1.0419x; 1.0419x over previous
//
#include <hip/hip_runtime.h>
#include <hip/hip_bf16.h>

#define B_ 128
#define S_ 513
#define H_ 256
#define SH_ (S_ * H_)

typedef __attribute__((ext_vector_type(8))) short short8;
typedef __attribute__((ext_vector_type(4))) float f32x4;

// Pack 8 fp32 -> 8 bf16 (RNE) via the HW packed converter.
static __device__ inline short8 pack8(float4 a, float4 b) {
    union { short8 s; __hip_bfloat162 h[4]; } u;
    u.h[0] = __float22bfloat162_rn(make_float2(a.x, a.y));
    u.h[1] = __float22bfloat162_rn(make_float2(a.z, a.w));
    u.h[2] = __float22bfloat162_rn(make_float2(b.x, b.y));
    u.h[3] = __float22bfloat162_rn(make_float2(b.z, b.w));
    return u.s;
}

// Prep: W fp32 -> bf16 in fragment-major layout (m, kc, d, 8) so the main
// kernel's per-kk W fragment loads are coalesced (16 lanes -> 256 B run).
// Also bias sum (256 floats).
__global__ void prep_kernel(const float* __restrict__ W,
                            const float* __restrict__ bias,
                            unsigned short* __restrict__ Wbf,
                            float* __restrict__ bsum) {
    int t = blockIdx.x * 256 + threadIdx.x;
    if (t < 5 * 32 * 256) {                 // one thread per (m, d, kc)
        int m  = t >> 13;                   // t / 8192
        int r  = t & 8191;
        int d  = r >> 5;
        int kc = r & 31;                    // 8-elem k-chunk
        const float* src = W + (((size_t)m * 256 + d) * 256 + kc * 8);
        float4 v0 = *(const float4*)src;
        float4 v1 = *(const float4*)(src + 4);
        *(short8*)(Wbf + ((size_t)(m * 32 + kc) * 256 + d) * 8) = pack8(v0, v1);
    }
    if (t < H_) {
        float s = 0.f;
#pragma unroll
        for (int i = 0; i < 5; ++i) s += bias[i * H_ + t];
        bsum[t] = s;
    }
}

// One block = one (s, batch-half): M=64, N=256, K=256.
// 256 threads = 4 waves, each owning a 64(b) x 64(d) tile via 4x4 MFMA frags.
// 32 KB LDS + <=128 VGPR -> 4 independent blocks/CU (vs 2 before): four
// phase-offset streams per CU keep HBM busy through compute/barrier phases,
// and grid 1026 ~ fully resident (no coarse dispatch tail).
//
// Operands are SWAPPED vs the previous version: A=W frag, B=x frag, so
// C/D has col=batch, row=d  ->  per-lane float4 stores along d.
// W fragments are (re)loaded from L2 inside the K-loop (16 live VGPRs
// instead of 128) -- W is only 640 KB total, hot in every XCD L2.
template <int MODE>
__global__ __launch_bounds__(256, 4)
void sel_gemm_kernel(const float* __restrict__ x,
                     const void* __restrict__ Wp,
                     const void* __restrict__ bp,
                     float* __restrict__ out) {
    const int s     = blockIdx.x >> 1;      // 0..512
    const int bhalf = blockIdx.x & 1;       // batch half: rows bhalf*64 ..
    const int m_idx = (s < 3) ? s : ((s & 1) ? 3 : 4);

    // 64 rows x 256 bf16 = 32 KB. 16-B chunk c of row r stored at c ^ (r&7):
    // fragment reads land 2 lanes/16B-slot (free); staging writes stay
    // conflict-free (XOR permutes within 128-B stripes).
    __shared__ unsigned short As[64 * 256];

    const int t    = threadIdx.x;
    const int lane = t & 63;
    const int w    = t >> 6;        // 0..3 : d-slice (w*64)
    const int lrow = lane & 15;
    const int quad = lane >> 4;

    // ---- Stage x: 64 rows x 256 fp32 -> bf16 LDS, swizzled. 8 chunks/thr.
    const float* xs = x + (size_t)s * H_ + (size_t)bhalf * 64 * SH_;
#pragma unroll
    for (int i = 0; i < 8; ++i) {
        int flat = i * 256 + t;
        int r = flat >> 5;              // 0..63 (batch row within half)
        int c = flat & 31;              // 16-B chunk (8 bf16) within row
        const float* src = xs + (size_t)r * SH_ + c * 8;
        float4 v0 = *(const float4*)src;
        float4 v1 = *(const float4*)(src + 4);
        *(short8*)&As[r * 256 + ((c ^ (r & 7)) * 8)] = pack8(v0, v1);
    }

    f32x4 acc[4][4];
#pragma unroll
    for (int i = 0; i < 4; ++i)
#pragma unroll
        for (int j = 0; j < 4; ++j) {
            f32x4 z = {0.f, 0.f, 0.f, 0.f};
            acc[i][j] = z;
        }

    __syncthreads();   // the only barrier

    // ---- K-loop: 8 steps of 32. W frags loaded per step (L2-hot).
#pragma unroll
    for (int kk = 0; kk < 8; ++kk) {
        short8 wfr[4];
        if (MODE == 0) {
            // layout (m, kc, d, 8): lane reads d = w*64 + j*16 + lrow,
            // kc = kk*4 + quad -> 16 lanes = 256 B contiguous.
            const unsigned short* Wk =
                (const unsigned short*)Wp +
                ((size_t)(m_idx * 32 + kk * 4 + quad) * 256) * 8;
#pragma unroll
            for (int j = 0; j < 4; ++j)
                wfr[j] = *(const short8*)(Wk + (size_t)(w * 64 + j * 16 + lrow) * 8);
        } else {
            const float* Wb = (const float*)Wp + (size_t)m_idx * H_ * H_;
#pragma unroll
            for (int j = 0; j < 4; ++j) {
                const float* wrow = Wb + (size_t)(w * 64 + j * 16 + lrow) * H_
                                    + kk * 32 + quad * 8;
                float4 v0 = *(const float4*)wrow;
                float4 v1 = *(const float4*)(wrow + 4);
                wfr[j] = pack8(v0, v1);
            }
        }

        short8 xfr[4];
        const int cc = kk * 4 + quad;   // chunk column of this lane's frag
#pragma unroll
        for (int i = 0; i < 4; ++i) {
            int r = i * 16 + lrow;
            xfr[i] = *(const short8*)&As[r * 256 + ((cc ^ (r & 7)) * 8)];
        }

#pragma unroll
        for (int j = 0; j < 4; ++j)
#pragma unroll
            for (int i = 0; i < 4; ++i)
                acc[i][j] = __builtin_amdgcn_mfma_f32_16x16x32_bf16(
                    wfr[j], xfr[i], acc[i][j], 0, 0, 0);
    }

    // ---- Epilogue. A=W, B=x  ->  col(lane&15)=batch, row(quad*4+reg)=d.
    // Per (i,j): one float4 store along d. 16 stores/lane total.
#pragma unroll
    for (int j = 0; j < 4; ++j) {
        const int d0 = w * 64 + j * 16 + quad * 4;
        f32x4 bj;
        if (MODE == 0) {
            bj = *(const f32x4*)((const float*)bp + d0);
        } else {
            const float* bias = (const float*)bp;
#pragma unroll
            for (int r = 0; r < 4; ++r) {
                float sum = 0.f;
#pragma unroll
                for (int i = 0; i < 5; ++i) sum += bias[i * H_ + d0 + r];
                bj[r] = sum;
            }
        }
#pragma unroll
        for (int i = 0; i < 4; ++i) {
            const int b = bhalf * 64 + i * 16 + lrow;
            f32x4 v = acc[i][j] + bj;
            *(f32x4*)(out + ((size_t)b * S_ + s) * H_ + d0) = v;
        }
    }
}

extern "C" void kernel_launch(void* const* d_in, const int* in_sizes, int n_in,
                              void* d_out, int out_size, void* d_ws, size_t ws_size,
                              hipStream_t stream) {
    const float* x    = (const float*)d_in[0];
    const float* W    = (const float*)d_in[1];
    const float* bias = (const float*)d_in[2];
    float* out = (float*)d_out;

    const size_t w_elems  = (size_t)5 * H_ * H_;
    const size_t ws_need  = w_elems * sizeof(unsigned short) + H_ * sizeof(float);

    if (ws_size >= ws_need) {
        unsigned short* Wbf = (unsigned short*)d_ws;
        float* bsum = (float*)((char*)d_ws + w_elems * sizeof(unsigned short));
        prep_kernel<<<dim3(160), dim3(256), 0, stream>>>(W, bias, Wbf, bsum);
        sel_gemm_kernel<0><<<dim3(2 * S_), dim3(256), 0, stream>>>(
            x, (const void*)Wbf, (const void*)bsum, out);
    } else {
        sel_gemm_kernel<1><<<dim3(2 * S_), dim3(256), 0, stream>>>(
            x, (const void*)W, (const void*)bias, out);
    }
}